// Round 5
// baseline (202.337 us; speedup 1.0000x reference)
//
#include <hip/hip_runtime.h>
#include <hip/hip_bf16.h>

#define DD 128
#define NPTS 8192
#define BBATCH 32
#define BK 64
#define LAM 0.01f

typedef __attribute__((ext_vector_type(8))) short bf16x8;
typedef __attribute__((ext_vector_type(16))) float f32x16;

__device__ __forceinline__ unsigned f2bf_u(float f) {
    unsigned u = __builtin_bit_cast(unsigned, f);
    return (u + 0x7FFFu + ((u >> 16) & 1u)) >> 16;
}
__device__ __forceinline__ float bf2f(unsigned short u) {
    unsigned v = ((unsigned)u) << 16;
    return __builtin_bit_cast(float, v);
}
__device__ __forceinline__ int swz(int d) { return ((d >> 2) ^ d) & 7; }

// raw barrier/waits: no compiler-inserted vmcnt(0) drain (m139 idiom)
#define ASM_BARRIER()  asm volatile("s_barrier" ::: "memory")
#define WAIT_VM4()     asm volatile("s_waitcnt vmcnt(4)" ::: "memory")
#define WAIT_VM0()     asm volatile("s_waitcnt vmcnt(0)" ::: "memory")
#define WAIT_LGKM0()   asm volatile("s_waitcnt lgkmcnt(0)" ::: "memory")

__device__ __forceinline__ void dma16(const void* g, void* l) {
    __builtin_amdgcn_global_load_lds(
        (const __attribute__((address_space(1))) void*)g,
        (__attribute__((address_space(3))) void*)l, 16, 0, 0);
}

// Kernel 1: per (batch, k-chunk) partial Gram via bf16 MFMA.
// global->LDS DMA staging, 3-deep circular raw buffer (tiles t+1,t+2 always in
// flight), 2 bf16 XT ping-pong. Raw s_barrier + manual vmcnt(4) keeps lookahead
// DMAs alive across barriers. fp32 csum/kdot from LDS for exact sort keys.
template<int P>
__global__ __launch_bounds__(512) void gram_stats(
    const float* __restrict__ x, unsigned short* __restrict__ Spart,
    float* __restrict__ CSpart, float* __restrict__ KDpart)
{
    __shared__ char smem[3 * 32768 + 2 * 16384];   // 128 KB
    short* XT = (short*)(smem + 98304);            // 2 x 8192 bf16

    constexpr int rowsPerBlk = NPTS / P;
    constexpr int T = rowsPerBlk / BK;

    const int blk = blockIdx.x;
    const int b   = blk & 31;
    const int kc  = blk >> 5;
    const float* xb = x + (size_t)b * NPTS * DD + (size_t)(kc * rowsPerBlk) * DD;

    const int tid    = threadIdx.x;
    const int lane   = tid & 63;
    const int wave   = tid >> 6;      // 0..7
    const int dg     = tid & 31;      // owns cols 4*dg+i
    const int rowgrp = tid >> 5;      // 0..15, owns rows rowgrp*4+r of the tile
    const int chunk  = rowgrp >> 1;
    const int wr32   = (wave & 3) * 32;
    const int wc64   = (wave >> 2) * 64;

    f32x16 acc0 = {}; f32x16 acc1 = {};
    float csum[4] = {0.f, 0.f, 0.f, 0.f};
    float kdot[4] = {0.f, 0.f, 0.f, 0.f};

    auto dmaTile = [&](int t) {
        const char* g = (const char*)(xb + (size_t)t * BK * DD) + wave * 4096 + lane * 16;
        char* l = smem + (t % 3) * 32768 + wave * 4096;
        dma16(g,        l);
        dma16(g + 1024, l + 1024);
        dma16(g + 2048, l + 2048);
        dma16(g + 3072, l + 3072);
    };

    dmaTile(0);
    dmaTile(1);

    for (int t = 0; t < T; ++t) {
        if (t < T - 1) { WAIT_VM4(); } else { WAIT_VM0(); }   // tile t landed (mine)
        ASM_BARRIER();                                        // ... and everyone's

        // ---- convert phase: raw fp32 tile -> swizzled bf16 XT + fp32 stats ----
        const float* rw = (const float*)(smem + (t % 3) * 32768);
        float4 R[4];
        float xk[4];
        #pragma unroll
        for (int r = 0; r < 4; ++r) {
            const int row = rowgrp * 4 + r;
            R[r]  = *(const float4*)(rw + row * DD + dg * 4);
            xk[r] = rw[row * DD];                 // col-0 broadcast (same addr/lane)
        }
        short* Xb = XT + (t & 1) * 8192;
        #pragma unroll
        for (int i = 0; i < 4; ++i) {
            const float v0 = (&R[0].x)[i], v1 = (&R[1].x)[i];
            const float v2 = (&R[2].x)[i], v3 = (&R[3].x)[i];
            csum[i] += v0 + v1 + v2 + v3;
            kdot[i] += xk[0] * v0 + xk[1] * v1 + xk[2] * v2 + xk[3] * v3;
            const int d = 4 * dg + i;
            unsigned u0 = f2bf_u(v0) | (f2bf_u(v1) << 16);
            unsigned u1 = f2bf_u(v2) | (f2bf_u(v3) << 16);
            const int addr = d * BK + ((chunk ^ swz(d)) * 8) + (rowgrp & 1) * 4;
            uint2 vv; vv.x = u0; vv.y = u1;
            *(uint2*)(Xb + addr) = vv;
        }
        WAIT_LGKM0();        // publish XT writes
        ASM_BARRIER();

        if (t + 2 < T) dmaTile(t + 2);   // lookahead DMA rides across barriers

        // ---- MFMA phase ----
        const short* Xc = XT + (t & 1) * 8192;
        #pragma unroll
        for (int ks = 0; ks < BK / 16; ++ks) {
            const int cb = ks * 2 + (lane >> 5);
            const int m = lane & 31;
            const int ad = wr32 + m, b0d = wc64 + m, b1d = wc64 + 32 + m;
            bf16x8 a  = *(const bf16x8*)(Xc + ad  * BK + ((cb ^ swz(ad))  * 8));
            bf16x8 b0 = *(const bf16x8*)(Xc + b0d * BK + ((cb ^ swz(b0d)) * 8));
            bf16x8 b1 = *(const bf16x8*)(Xc + b1d * BK + ((cb ^ swz(b1d)) * 8));
            acc0 = __builtin_amdgcn_mfma_f32_32x32x16_bf16(a, b0, acc0, 0, 0, 0);
            acc1 = __builtin_amdgcn_mfma_f32_32x32x16_bf16(a, b1, acc1, 0, 0, 0);
        }
    }

    // ---- epilogue: Spart bf16 (C/D: col=lane&31, row=(r&3)+8*(r>>2)+4*(lane>>5)) ----
    unsigned short* Sp = Spart + ((size_t)b * P + kc) * (DD * DD);
    const int colLane = lane & 31;
    const int rowHw = 4 * (lane >> 5);
    #pragma unroll
    for (int r = 0; r < 16; ++r) {
        const int row = wr32 + (r & 3) + 8 * (r >> 2) + rowHw;
        Sp[row * DD + wc64 + colLane]      = (unsigned short)f2bf_u(acc0[r]);
        Sp[row * DD + wc64 + 32 + colLane] = (unsigned short)f2bf_u(acc1[r]);
    }

    // ---- block-reduce colsum / keydot (no DMAs outstanding; __syncthreads ok) ----
    __syncthreads();
    float* red = (float*)smem;
    #pragma unroll
    for (int i = 0; i < 4; ++i) {
        red[tid] = csum[i];
        __syncthreads();
        if (tid < 32) {
            float s = 0.f;
            #pragma unroll
            for (int g = 0; g < 16; ++g) s += red[g * 32 + tid];
            CSpart[((size_t)b * P + kc) * DD + 4 * tid + i] = s;
        }
        __syncthreads();
        red[tid] = kdot[i];
        __syncthreads();
        if (tid < 32) {
            float s = 0.f;
            #pragma unroll
            for (int g = 0; g < 16; ++g) s += red[g * 32 + tid];
            KDpart[((size_t)b * P + kc) * DD + 4 * tid + i] = s;
        }
        __syncthreads();
    }
}

// Kernel 2: one block per batch — reduce fp32 colsums/key-dots, compute keys,
// rank rows by fp32 key (index tie-break), store cs + ranks.
template<int P>
__global__ __launch_bounds__(128) void keys_ranks(
    const float* __restrict__ CSpart, const float* __restrict__ KDpart,
    float* __restrict__ csOut, int* __restrict__ rankOut)
{
    __shared__ float csh[DD];
    __shared__ float key[DD];
    const int b = blockIdx.x;
    const int tid = threadIdx.x;
    float s = 0.f, kd = 0.f;
    #pragma unroll
    for (int p = 0; p < P; ++p) {
        s  += CSpart[((size_t)b * P + p) * DD + tid];
        kd += KDpart[((size_t)b * P + p) * DD + tid];
    }
    csh[tid] = s;
    __syncthreads();
    const float k = (kd - s * csh[0] * (1.f / NPTS)) * (1.f / (NPTS - 1))
                  + ((tid == 0) ? LAM : 0.f);
    key[tid] = k;
    __syncthreads();
    int r = 0;
    #pragma unroll 8
    for (int j = 0; j < DD; ++j) {
        const float kj = key[j];
        r += (kj < k) || (kj == k && j < tid);
    }
    csOut[b * DD + tid] = s;
    rankOut[b * DD + tid] = r;
}

// Kernel 3: block (b, seg of 8 rows) — reduce bf16 partial Grams, fixup
// mean/ridge, scatter rows to ranked position in d_out.
template<int P>
__global__ __launch_bounds__(256) void reduce_scatter(
    const unsigned short* __restrict__ Spart, const float* __restrict__ csOut,
    const int* __restrict__ rankOut, float* __restrict__ out)
{
    __shared__ float csh[DD];
    __shared__ int rk[8];
    const int b = blockIdx.x;
    const int seg = blockIdx.y;
    const int tid = threadIdx.x;
    if (tid < DD) csh[tid] = csOut[b * DD + tid];
    if (tid < 8)  rk[tid] = rankOut[b * DD + seg * 8 + tid];

    const int base = seg * (8 * DD) + tid * 4;
    float a0 = 0.f, a1 = 0.f, a2 = 0.f, a3 = 0.f;
    #pragma unroll
    for (int p = 0; p < P; ++p) {
        uint2 v = *(const uint2*)(Spart + ((size_t)b * P + p) * (DD * DD) + base);
        a0 += bf2f((unsigned short)(v.x & 0xFFFFu));
        a1 += bf2f((unsigned short)(v.x >> 16));
        a2 += bf2f((unsigned short)(v.y & 0xFFFFu));
        a3 += bf2f((unsigned short)(v.y >> 16));
    }
    __syncthreads();
    const int row = seg * 8 + (tid >> 5);
    const int j0  = (tid & 31) * 4;
    const float ci = csh[row];
    const float invN = 1.f / NPTS, invNm1 = 1.f / (NPTS - 1);
    float4 v;
    v.x = (a0 - ci * csh[j0 + 0] * invN) * invNm1 + ((row == j0 + 0) ? LAM : 0.f);
    v.y = (a1 - ci * csh[j0 + 1] * invN) * invNm1 + ((row == j0 + 1) ? LAM : 0.f);
    v.z = (a2 - ci * csh[j0 + 2] * invN) * invNm1 + ((row == j0 + 2) ? LAM : 0.f);
    v.w = (a3 - ci * csh[j0 + 3] * invN) * invNm1 + ((row == j0 + 3) ? LAM : 0.f);
    float* o = out + (size_t)b * DD * DD + (size_t)rk[tid >> 5] * DD + j0;
    *(float4*)o = v;
}

template<int P>
static void launch_all(const float* x, float* out, void* d_ws, hipStream_t stream)
{
    size_t nS = (size_t)BBATCH * P * DD * DD;           // shorts
    unsigned short* Spart = (unsigned short*)d_ws;
    float* CSpart = (float*)(Spart + nS);
    float* KDpart = CSpart + (size_t)BBATCH * P * DD;
    float* csOut  = KDpart + (size_t)BBATCH * P * DD;
    int*   rankOut = (int*)(csOut + (size_t)BBATCH * DD);

    gram_stats<P><<<dim3(32 * P), dim3(512), 0, stream>>>(x, Spart, CSpart, KDpart);
    keys_ranks<P><<<dim3(BBATCH), dim3(128), 0, stream>>>(CSpart, KDpart, csOut, rankOut);
    reduce_scatter<P><<<dim3(BBATCH, 16), dim3(256), 0, stream>>>(Spart, csOut, rankOut, out);
}

extern "C" void kernel_launch(void* const* d_in, const int* in_sizes, int n_in,
                              void* d_out, int out_size, void* d_ws, size_t ws_size,
                              hipStream_t stream)
{
    const float* x = (const float*)d_in[0];
    float* out = (float*)d_out;

    auto need = [](int P) {
        return (size_t)BBATCH * P * DD * DD * sizeof(unsigned short)
             + (size_t)BBATCH * P * 2 * DD * sizeof(float)
             + (size_t)BBATCH * DD * (sizeof(float) + sizeof(int));
    };
    if (need(8) <= ws_size)       launch_all<8>(x, out, d_ws, stream);
    else                          launch_all<4>(x, out, d_ws, stream);
}

// Round 6
// 200.456 us; speedup vs baseline: 1.0094x; 1.0094x over previous
//
#include <hip/hip_runtime.h>
#include <hip/hip_bf16.h>

#define DD 128
#define NPTS 8192
#define BBATCH 32
#define BK 64
#define LAM 0.01f

typedef __attribute__((ext_vector_type(8))) short bf16x8;
typedef __attribute__((ext_vector_type(16))) float f32x16;

__device__ __forceinline__ unsigned f2bf_u(float f) {
    unsigned u = __builtin_bit_cast(unsigned, f);
    return (u + 0x7FFFu + ((u >> 16) & 1u)) >> 16;
}
__device__ __forceinline__ float bf2f(unsigned short u) {
    unsigned v = ((unsigned)u) << 16;
    return __builtin_bit_cast(float, v);
}
__device__ __forceinline__ int swz(int d) { return ((d >> 2) ^ d) & 7; }

// raw barrier/waits: avoid __syncthreads' mandatory vmcnt(0) drain (m97/m139)
#define ASM_BARRIER()  asm volatile("s_barrier" ::: "memory")
#define WAIT_LGKM0()   asm volatile("s_waitcnt lgkmcnt(0)" ::: "memory")

// Kernel 1: per (batch, k-chunk) partial Gram via bf16 MFMA.
// Register-staged (no LDS-DMA aliasing), 2-tile lookahead in VGPRs, raw
// s_barrier + lgkmcnt(0) only -> prefetch loads stay in flight across the
// barrier. One barrier per tile. fp32 csum/kdot for exact sort keys.
template<int P>
__global__ __launch_bounds__(512, 4) void gram_stats(
    const float* __restrict__ x, unsigned short* __restrict__ Spart,
    float* __restrict__ CSpart, float* __restrict__ KDpart)
{
    __shared__ short XT[2][DD * BK];   // ping-pong, 2 x 16 KB
    constexpr int rowsPerBlk = NPTS / P;
    constexpr int T = rowsPerBlk / BK;   // even

    const int blk = blockIdx.x;
    const int b   = blk & 31;
    const int kc  = blk >> 5;
    const float* xb = x + (size_t)b * NPTS * DD + (size_t)(kc * rowsPerBlk) * DD;

    const int tid    = threadIdx.x;
    const int lane   = tid & 63;
    const int wave   = tid >> 6;      // 0..7
    const int dg     = tid & 31;      // owns cols 4*dg+i of its rows
    const int rowgrp = tid >> 5;      // 0..15, owns rows rowgrp*4+r of the tile
    const int chunk  = rowgrp >> 1;
    const int wr32   = (wave & 3) * 32;
    const int wc64   = (wave >> 2) * 64;

    f32x16 acc0 = {}; f32x16 acc1 = {};
    float csum[4] = {0.f, 0.f, 0.f, 0.f};
    float kdot[4] = {0.f, 0.f, 0.f, 0.f};
    float4 RA[4], RB[4];

    auto issueLoads = [&](float4* R, int t) {
        const float4* s = (const float4*)(xb + (size_t)(t * BK + rowgrp * 4) * DD) + dg;
        R[0] = s[0]; R[1] = s[32]; R[2] = s[64]; R[3] = s[96];
    };
    auto convertStore = [&](float4* R, int buf) {
        float x00 = __shfl(R[0].x, lane & 32);
        float x01 = __shfl(R[1].x, lane & 32);
        float x02 = __shfl(R[2].x, lane & 32);
        float x03 = __shfl(R[3].x, lane & 32);
        short* Xb = XT[buf];
        #pragma unroll
        for (int i = 0; i < 4; ++i) {
            const float v0 = (&R[0].x)[i], v1 = (&R[1].x)[i];
            const float v2 = (&R[2].x)[i], v3 = (&R[3].x)[i];
            csum[i] += v0 + v1 + v2 + v3;
            kdot[i] += x00 * v0 + x01 * v1 + x02 * v2 + x03 * v3;
            const int d = 4 * dg + i;
            unsigned u0 = f2bf_u(v0) | (f2bf_u(v1) << 16);
            unsigned u1 = f2bf_u(v2) | (f2bf_u(v3) << 16);
            const int addr = d * BK + ((chunk ^ swz(d)) * 8) + (rowgrp & 1) * 4;
            uint2 vv; vv.x = u0; vv.y = u1;
            *(uint2*)(Xb + addr) = vv;
        }
    };
    auto mfmaPhase = [&](const short* Xc) {
        #pragma unroll
        for (int ks = 0; ks < BK / 16; ++ks) {
            const int cb = ks * 2 + (lane >> 5);
            const int m = lane & 31;
            const int ad = wr32 + m, b0d = wc64 + m, b1d = wc64 + 32 + m;
            bf16x8 a  = *(const bf16x8*)(Xc + ad  * BK + ((cb ^ swz(ad))  * 8));
            bf16x8 b0 = *(const bf16x8*)(Xc + b0d * BK + ((cb ^ swz(b0d)) * 8));
            bf16x8 b1 = *(const bf16x8*)(Xc + b1d * BK + ((cb ^ swz(b1d)) * 8));
            acc0 = __builtin_amdgcn_mfma_f32_32x32x16_bf16(a, b0, acc0, 0, 0, 0);
            acc1 = __builtin_amdgcn_mfma_f32_32x32x16_bf16(a, b1, acc1, 0, 0, 0);
        }
    };

    issueLoads(RA, 0);
    issueLoads(RB, 1);
    convertStore(RA, 0);          // waits only RA's loads; RB stays in flight
    WAIT_LGKM0(); ASM_BARRIER();  // publish XT[0]

    for (int tt = 0; tt < T; tt += 2) {
        // even tile tt (XT[0], buffer RA just consumed)
        if (tt + 2 < T) issueLoads(RA, tt + 2);   // in flight across mfma+conv+barrier
        mfmaPhase(XT[0]);
        convertStore(RB, 1);                      // tile tt+1 -> XT[1]
        WAIT_LGKM0(); ASM_BARRIER();
        // odd tile tt+1 (XT[1], buffer RB just consumed)
        if (tt + 3 < T) issueLoads(RB, tt + 3);
        mfmaPhase(XT[1]);
        if (tt + 2 < T) {
            convertStore(RA, 0);                  // tile tt+2 -> XT[0]
            WAIT_LGKM0(); ASM_BARRIER();
        }
    }

    // epilogue: Spart bf16 (C/D: col=lane&31, row=(r&3)+8*(r>>2)+4*(lane>>5))
    unsigned short* Sp = Spart + ((size_t)b * P + kc) * (DD * DD);
    const int colLane = lane & 31;
    const int rowHw = 4 * (lane >> 5);
    #pragma unroll
    for (int r = 0; r < 16; ++r) {
        const int row = wr32 + (r & 3) + 8 * (r >> 2) + rowHw;
        Sp[row * DD + wc64 + colLane]      = (unsigned short)f2bf_u(acc0[r]);
        Sp[row * DD + wc64 + 32 + colLane] = (unsigned short)f2bf_u(acc1[r]);
    }

    // block-reduce colsum / keydot (no loads outstanding; __syncthreads fine)
    __syncthreads();
    float* red = (float*)XT;
    #pragma unroll
    for (int i = 0; i < 4; ++i) {
        red[tid] = csum[i];
        __syncthreads();
        if (tid < 32) {
            float s = 0.f;
            #pragma unroll
            for (int g = 0; g < 16; ++g) s += red[g * 32 + tid];
            CSpart[((size_t)b * P + kc) * DD + 4 * tid + i] = s;
        }
        __syncthreads();
        red[tid] = kdot[i];
        __syncthreads();
        if (tid < 32) {
            float s = 0.f;
            #pragma unroll
            for (int g = 0; g < 16; ++g) s += red[g * 32 + tid];
            KDpart[((size_t)b * P + kc) * DD + 4 * tid + i] = s;
        }
        __syncthreads();
    }
}

// Kernel 2: one block per batch — reduce fp32 colsums/key-dots, compute keys,
// rank rows by fp32 key (index tie-break), store cs + ranks.
template<int P>
__global__ __launch_bounds__(128) void keys_ranks(
    const float* __restrict__ CSpart, const float* __restrict__ KDpart,
    float* __restrict__ csOut, int* __restrict__ rankOut)
{
    __shared__ float csh[DD];
    __shared__ float key[DD];
    const int b = blockIdx.x;
    const int tid = threadIdx.x;
    float s = 0.f, kd = 0.f;
    #pragma unroll
    for (int p = 0; p < P; ++p) {
        s  += CSpart[((size_t)b * P + p) * DD + tid];
        kd += KDpart[((size_t)b * P + p) * DD + tid];
    }
    csh[tid] = s;
    __syncthreads();
    const float k = (kd - s * csh[0] * (1.f / NPTS)) * (1.f / (NPTS - 1))
                  + ((tid == 0) ? LAM : 0.f);
    key[tid] = k;
    __syncthreads();
    int r = 0;
    #pragma unroll 8
    for (int j = 0; j < DD; ++j) {
        const float kj = key[j];
        r += (kj < k) || (kj == k && j < tid);
    }
    csOut[b * DD + tid] = s;
    rankOut[b * DD + tid] = r;
}

// Kernel 3: block (b, seg of 8 rows) — reduce bf16 partial Grams, fixup
// mean/ridge, scatter rows to ranked position in d_out.
template<int P>
__global__ __launch_bounds__(256) void reduce_scatter(
    const unsigned short* __restrict__ Spart, const float* __restrict__ csOut,
    const int* __restrict__ rankOut, float* __restrict__ out)
{
    __shared__ float csh[DD];
    __shared__ int rk[8];
    const int b = blockIdx.x;
    const int seg = blockIdx.y;
    const int tid = threadIdx.x;
    if (tid < DD) csh[tid] = csOut[b * DD + tid];
    if (tid < 8)  rk[tid] = rankOut[b * DD + seg * 8 + tid];

    const int base = seg * (8 * DD) + tid * 4;
    float a0 = 0.f, a1 = 0.f, a2 = 0.f, a3 = 0.f;
    #pragma unroll
    for (int p = 0; p < P; ++p) {
        uint2 v = *(const uint2*)(Spart + ((size_t)b * P + p) * (DD * DD) + base);
        a0 += bf2f((unsigned short)(v.x & 0xFFFFu));
        a1 += bf2f((unsigned short)(v.x >> 16));
        a2 += bf2f((unsigned short)(v.y & 0xFFFFu));
        a3 += bf2f((unsigned short)(v.y >> 16));
    }
    __syncthreads();
    const int row = seg * 8 + (tid >> 5);
    const int j0  = (tid & 31) * 4;
    const float ci = csh[row];
    const float invN = 1.f / NPTS, invNm1 = 1.f / (NPTS - 1);
    float4 v;
    v.x = (a0 - ci * csh[j0 + 0] * invN) * invNm1 + ((row == j0 + 0) ? LAM : 0.f);
    v.y = (a1 - ci * csh[j0 + 1] * invN) * invNm1 + ((row == j0 + 1) ? LAM : 0.f);
    v.z = (a2 - ci * csh[j0 + 2] * invN) * invNm1 + ((row == j0 + 2) ? LAM : 0.f);
    v.w = (a3 - ci * csh[j0 + 3] * invN) * invNm1 + ((row == j0 + 3) ? LAM : 0.f);
    float* o = out + (size_t)b * DD * DD + (size_t)rk[tid >> 5] * DD + j0;
    *(float4*)o = v;
}

template<int P>
static void launch_all(const float* x, float* out, void* d_ws, hipStream_t stream)
{
    size_t nS = (size_t)BBATCH * P * DD * DD;           // shorts
    unsigned short* Spart = (unsigned short*)d_ws;
    float* CSpart = (float*)(Spart + nS);
    float* KDpart = CSpart + (size_t)BBATCH * P * DD;
    float* csOut  = KDpart + (size_t)BBATCH * P * DD;
    int*   rankOut = (int*)(csOut + (size_t)BBATCH * DD);

    gram_stats<P><<<dim3(32 * P), dim3(512), 0, stream>>>(x, Spart, CSpart, KDpart);
    keys_ranks<P><<<dim3(BBATCH), dim3(128), 0, stream>>>(CSpart, KDpart, csOut, rankOut);
    reduce_scatter<P><<<dim3(BBATCH, 16), dim3(256), 0, stream>>>(Spart, csOut, rankOut, out);
}

extern "C" void kernel_launch(void* const* d_in, const int* in_sizes, int n_in,
                              void* d_out, int out_size, void* d_ws, size_t ws_size,
                              hipStream_t stream)
{
    const float* x = (const float*)d_in[0];
    float* out = (float*)d_out;

    auto need = [](int P) {
        return (size_t)BBATCH * P * DD * DD * sizeof(unsigned short)
             + (size_t)BBATCH * P * 2 * DD * sizeof(float)
             + (size_t)BBATCH * DD * (sizeof(float) + sizeof(int));
    };
    if (need(16) <= ws_size)      launch_all<16>(x, out, d_ws, stream);
    else                          launch_all<8>(x, out, d_ws, stream);
}